// Round 1
// baseline (257.240 us; speedup 1.0000x reference)
//
#include <hip/hip_runtime.h>
#include <hip/hip_bf16.h>

typedef unsigned short u16;
typedef float f32x4v __attribute__((ext_vector_type(4)));
typedef short short8 __attribute__((ext_vector_type(8)));

#define TSEQ 512
#define EMB  1024
#define DI   2048
#define NH   32
#define DS   64
#define PROJ 4256
#define PROJP 4352
#define NCH  8    // chunks
#define LCH  64   // chunk length

__device__ __forceinline__ u16 f2bf(float f) {
    union { __hip_bfloat16 h; u16 u; } cv;
    cv.h = __float2bfloat16(f);
    return cv.u;
}
__device__ __forceinline__ unsigned pack2(float a, float b) {
    return (unsigned)f2bf(a) | ((unsigned)f2bf(b) << 16);
}

// ---------------- transpose + cast f32 (K x N) -> bf16 (Npad x K), zero-pad n >= N
__global__ __launch_bounds__(256) void k_transpose_cast(
        const float* __restrict__ src, u16* __restrict__ dst, int K, int N) {
    __shared__ float tile[64][65];
    const int n0 = blockIdx.x * 64;
    const int k0 = blockIdx.y * 64;
    const int tid = threadIdx.x;
    const int c  = tid & 63;   // n-within (load)
    const int r4 = tid >> 6;
    #pragma unroll
    for (int i = 0; i < 16; ++i) {
        int r = r4 + i * 4;    // k-within
        float v = 0.f;
        if (n0 + c < N) v = src[(size_t)(k0 + r) * N + n0 + c];
        tile[r][c] = v;
    }
    __syncthreads();
    const int rk = tid & 63;   // k-within (store)
    const int cn = tid >> 6;
    #pragma unroll
    for (int i = 0; i < 16; ++i) {
        int n = cn + i * 4;    // n-within
        dst[(size_t)(n0 + n) * K + k0 + rk] = f2bf(tile[rk][n]);
    }
}

// ---------------- RMSNorm -> bf16
__global__ __launch_bounds__(256) void k_rmsnorm(
        const float* __restrict__ x, const float* __restrict__ scale,
        u16* __restrict__ xnb) {
    const int t = blockIdx.x, tid = threadIdx.x;
    const float4* xr = (const float4*)(x + (size_t)t * EMB);
    float4 v = xr[tid];
    float ss = v.x * v.x + v.y * v.y + v.z * v.z + v.w * v.w;
    #pragma unroll
    for (int off = 32; off; off >>= 1) ss += __shfl_xor(ss, off);
    __shared__ float ws4[4];
    if ((tid & 63) == 0) ws4[tid >> 6] = ss;
    __syncthreads();
    float tot = ws4[0] + ws4[1] + ws4[2] + ws4[3];
    float inv = rsqrtf(tot * (1.f / EMB) + 1e-6f);
    float4 s = ((const float4*)scale)[tid];
    uint2 o;
    o.x = pack2(v.x * inv * s.x, v.y * inv * s.y);
    o.y = pack2(v.z * inv * s.z, v.w * inv * s.w);
    ((uint2*)xnb)[(size_t)t * 256 + tid] = o;
}

// ---------------- bf16 MFMA GEMM: C[M x N] = A[M x K] * BT[N x K]^T (+ residual)
// 256 threads = 4 waves in 2x2; BK = 64.
template<int BM, int BN, int EPI>
__global__ __launch_bounds__(256) void k_gemm(
        const u16* __restrict__ A, int lda,
        const u16* __restrict__ BT, int ldb,
        float* __restrict__ C, int ldc, int K,
        const float* __restrict__ res) {
    constexpr int WM = BM / 2, WN = BN / 2, FM = WM / 16, FN = WN / 16;
    __shared__ __align__(16) u16 Al[BM][72];
    __shared__ __align__(16) u16 Bl[BN][72];
    const int tid = threadIdx.x;
    const int wid = tid >> 6, lane = tid & 63;
    const int wr = wid >> 1, wc = wid & 1;
    const int ar = lane & 15, kg = lane >> 4;
    const int row0 = blockIdx.y * BM, col0 = blockIdx.x * BN;
    f32x4v acc[FM][FN] = {};
    for (int k0 = 0; k0 < K; k0 += 64) {
        #pragma unroll
        for (int idx = tid; idx < BM * 8; idx += 256) {
            int r = idx >> 3, cc = idx & 7;
            short8 v = *(const short8*)(A + (size_t)(row0 + r) * lda + k0 + cc * 8);
            *(short8*)&Al[r][cc * 8] = v;
        }
        #pragma unroll
        for (int idx = tid; idx < BN * 8; idx += 256) {
            int r = idx >> 3, cc = idx & 7;
            short8 v = *(const short8*)(BT + (size_t)(col0 + r) * ldb + k0 + cc * 8);
            *(short8*)&Bl[r][cc * 8] = v;
        }
        __syncthreads();
        #pragma unroll
        for (int kk = 0; kk < 2; ++kk) {
            short8 af[FM], bf[FN];
            #pragma unroll
            for (int m = 0; m < FM; ++m)
                af[m] = *(const short8*)&Al[wr * WM + m * 16 + ar][kk * 32 + kg * 8];
            #pragma unroll
            for (int n = 0; n < FN; ++n)
                bf[n] = *(const short8*)&Bl[wc * WN + n * 16 + ar][kk * 32 + kg * 8];
            #pragma unroll
            for (int m = 0; m < FM; ++m)
                #pragma unroll
                for (int n = 0; n < FN; ++n)
                    acc[m][n] = __builtin_amdgcn_mfma_f32_16x16x32_bf16(
                        af[m], bf[n], acc[m][n], 0, 0, 0);
        }
        __syncthreads();
    }
    #pragma unroll
    for (int m = 0; m < FM; ++m)
        #pragma unroll
        for (int n = 0; n < FN; ++n)
            #pragma unroll
            for (int j = 0; j < 4; ++j) {
                int row = row0 + wr * WM + m * 16 + kg * 4 + j;
                int col = col0 + wc * WN + n * 16 + ar;
                float v = acc[m][n][j];
                if (EPI) v += res[(size_t)row * ldc + col];
                C[(size_t)row * ldc + col] = v;
            }
}

// ---------------- dt / A_bar
__global__ __launch_bounds__(256) void k_dt(
        const float* __restrict__ proj, const float* __restrict__ A_log,
        const float* __restrict__ dt_bias, float* __restrict__ dtw,
        float* __restrict__ abw) {
    int idx = blockIdx.x * 256 + threadIdx.x;   // < 512*32
    int t = idx >> 5, hh = idx & 31;
    float z = proj[(size_t)t * PROJP + 2 * DI + hh] + dt_bias[hh];
    float dt = (z > 20.f) ? z : log1pf(expf(z));
    float ab = expf(-expf(A_log[hh]) * dt);
    dtw[idx] = dt;
    abw[idx] = ab;
}

// ---------------- causal conv(4) + SiLU
__global__ __launch_bounds__(256) void k_conv(
        const float* __restrict__ proj, const float* __restrict__ cw,
        const float* __restrict__ cb, float* __restrict__ hout) {
    int idx = blockIdx.x * 256 + threadIdx.x;   // < 512*2048
    int t = idx >> 11, c = idx & 2047;
    float acc = cb[c];
    #pragma unroll
    for (int k = 0; k < 4; ++k) {
        int tt = t + k - 3;
        if (tt >= 0) acc += cw[k * DI + c] * proj[(size_t)tt * PROJP + DI + c];
    }
    hout[idx] = acc / (1.f + expf(-acc));
}

// ---------------- scan phase 1: per-(chunk,head) local end-state + decay product
__global__ __launch_bounds__(256) void k_scan1(
        const float* __restrict__ proj, const float* __restrict__ hconv,
        const float* __restrict__ dtw, const float* __restrict__ abw,
        float* __restrict__ Sloc, float* __restrict__ Pc) {
    const int c = blockIdx.x, h = blockIdx.y;
    const int tid = threadIdx.x;
    const int q = tid & 3, p = tid >> 2, n0 = q * 16;
    __shared__ __align__(16) float Blds[64][64];
    __shared__ __align__(16) float xl[64][64];
    __shared__ float al[64], dl[64];
    for (int i = tid; i < 4096; i += 256) {
        int t = i >> 6, n = i & 63;
        Blds[t][n] = proj[(size_t)(c * 64 + t) * PROJP + 2 * DI + NH + n];
        xl[t][n]   = hconv[(size_t)(c * 64 + t) * DI + h * 64 + n];
    }
    if (tid < 64) {
        al[tid] = abw[(c * 64 + tid) * NH + h];
        dl[tid] = dtw[(c * 64 + tid) * NH + h];
    }
    __syncthreads();
    float s[16] = {0.f,0.f,0.f,0.f,0.f,0.f,0.f,0.f,0.f,0.f,0.f,0.f,0.f,0.f,0.f,0.f};
    for (int t = 0; t < 64; ++t) {
        float a = al[t];
        float dtx = dl[t] * xl[t][p];
        const float4* brow = (const float4*)&Blds[t][n0];
        #pragma unroll
        for (int i4 = 0; i4 < 4; ++i4) {
            float4 b = brow[i4];
            s[i4*4+0] = a * s[i4*4+0] + dtx * b.x;
            s[i4*4+1] = a * s[i4*4+1] + dtx * b.y;
            s[i4*4+2] = a * s[i4*4+2] + dtx * b.z;
            s[i4*4+3] = a * s[i4*4+3] + dtx * b.w;
        }
    }
    float* dst = Sloc + ((size_t)(c * 32 + h) * 64 + p) * 64 + n0;
    #pragma unroll
    for (int i4 = 0; i4 < 4; ++i4)
        ((float4*)dst)[i4] = make_float4(s[i4*4], s[i4*4+1], s[i4*4+2], s[i4*4+3]);
    if (tid == 0) {
        float pr = 1.f;
        for (int t = 0; t < 64; ++t) pr *= al[t];
        Pc[c * 32 + h] = pr;
    }
}

// ---------------- scan phase 2: inter-chunk scan (tiny)
__global__ __launch_bounds__(256) void k_scan2(
        const float* __restrict__ Sloc, const float* __restrict__ Pc,
        float* __restrict__ Sinit) {
    int gid = blockIdx.x * 256 + threadIdx.x;   // < 32*4096
    int h = gid >> 12, rem = gid & 4095;
    float s = 0.f;
    #pragma unroll
    for (int c = 0; c < NCH; ++c) {
        size_t o = (size_t)(c * 32 + h) * 4096 + rem;
        Sinit[o] = s;
        s = Pc[c * 32 + h] * s + Sloc[o];
    }
}

// ---------------- scan phase 3: replay with outputs, fused gate*silu -> bf16
__global__ __launch_bounds__(256) void k_scan3(
        const float* __restrict__ proj, const float* __restrict__ hconv,
        const float* __restrict__ dtw, const float* __restrict__ abw,
        const float* __restrict__ Sinit, u16* __restrict__ yg) {
    const int c = blockIdx.x, h = blockIdx.y;
    const int tid = threadIdx.x;
    const int q = tid & 3, p = tid >> 2, n0 = q * 16;
    __shared__ __align__(16) float Blds[64][64];
    __shared__ __align__(16) float Clds[64][64];
    __shared__ __align__(16) float xl[64][64];
    __shared__ float al[64], dl[64];
    for (int i = tid; i < 4096; i += 256) {
        int t = i >> 6, n = i & 63;
        Blds[t][n] = proj[(size_t)(c * 64 + t) * PROJP + 2 * DI + NH + n];
        Clds[t][n] = proj[(size_t)(c * 64 + t) * PROJP + 2 * DI + NH + DS + n];
        xl[t][n]   = hconv[(size_t)(c * 64 + t) * DI + h * 64 + n];
    }
    if (tid < 64) {
        al[tid] = abw[(c * 64 + tid) * NH + h];
        dl[tid] = dtw[(c * 64 + tid) * NH + h];
    }
    __syncthreads();
    float s[16];
    const float* si = Sinit + ((size_t)(c * 32 + h) * 64 + p) * 64 + n0;
    #pragma unroll
    for (int i4 = 0; i4 < 4; ++i4) {
        float4 v = ((const float4*)si)[i4];
        s[i4*4+0] = v.x; s[i4*4+1] = v.y; s[i4*4+2] = v.z; s[i4*4+3] = v.w;
    }
    for (int t = 0; t < 64; ++t) {
        float a = al[t];
        float dtx = dl[t] * xl[t][p];
        const float4* brow = (const float4*)&Blds[t][n0];
        const float4* crow = (const float4*)&Clds[t][n0];
        float yp = 0.f;
        #pragma unroll
        for (int i4 = 0; i4 < 4; ++i4) {
            float4 b = brow[i4], cc = crow[i4];
            s[i4*4+0] = a * s[i4*4+0] + dtx * b.x; yp += s[i4*4+0] * cc.x;
            s[i4*4+1] = a * s[i4*4+1] + dtx * b.y; yp += s[i4*4+1] * cc.y;
            s[i4*4+2] = a * s[i4*4+2] + dtx * b.z; yp += s[i4*4+2] * cc.z;
            s[i4*4+3] = a * s[i4*4+3] + dtx * b.w; yp += s[i4*4+3] * cc.w;
        }
        yp += __shfl_xor(yp, 1);
        yp += __shfl_xor(yp, 2);
        if (q == 0) xl[t][p] = yp;   // reuse xl as y storage (same-wave safe)
    }
    __syncthreads();
    for (int i = tid; i < 4096; i += 256) {
        int t = i >> 6, pp = i & 63;
        float y = xl[t][pp];
        float g = proj[(size_t)(c * 64 + t) * PROJP + h * 64 + pp];
        float gy = y * (g / (1.f + expf(-g)));
        yg[(size_t)(c * 64 + t) * DI + h * 64 + pp] = f2bf(gy);
    }
}

extern "C" void kernel_launch(void* const* d_in, const int* in_sizes, int n_in,
                              void* d_out, int out_size, void* d_ws, size_t ws_size,
                              hipStream_t stream) {
    (void)in_sizes; (void)n_in; (void)out_size; (void)ws_size;
    const float* x       = (const float*)d_in[0];
    const float* nscale  = (const float*)d_in[1];
    const float* w_in    = (const float*)d_in[2];
    const float* conv_w  = (const float*)d_in[3];
    const float* conv_b  = (const float*)d_in[4];
    const float* A_log   = (const float*)d_in[5];
    const float* dt_bias = (const float*)d_in[6];
    const float* w_out   = (const float*)d_in[7];
    float* out = (float*)d_out;

    char* wsp = (char*)d_ws;
    auto alloc = [&](size_t bytes) {
        char* ptr = wsp;
        wsp += (bytes + 255) & ~(size_t)255;
        return ptr;
    };
    u16*   w_inT  = (u16*)  alloc((size_t)PROJP * 1024 * 2);
    u16*   w_outT = (u16*)  alloc((size_t)1024 * 2048 * 2);
    u16*   xnb    = (u16*)  alloc((size_t)512 * 1024 * 2);
    float* proj   = (float*)alloc((size_t)512 * PROJP * 4);
    float* hconv  = (float*)alloc((size_t)512 * 2048 * 4);
    float* dtw    = (float*)alloc((size_t)512 * 32 * 4);
    float* abw    = (float*)alloc((size_t)512 * 32 * 4);
    float* Pc     = (float*)alloc((size_t)256 * 4);
    float* Sloc   = (float*)alloc((size_t)NCH * 32 * 4096 * 4);
    float* Sinit  = (float*)alloc((size_t)NCH * 32 * 4096 * 4);
    u16*   yg     = (u16*)  alloc((size_t)512 * 2048 * 2);

    k_transpose_cast<<<dim3(68, 16), 256, 0, stream>>>(w_in, w_inT, 1024, PROJ);
    k_transpose_cast<<<dim3(16, 32), 256, 0, stream>>>(w_out, w_outT, 2048, 1024);
    k_rmsnorm<<<512, 256, 0, stream>>>(x, nscale, xnb);
    k_gemm<128, 128, 0><<<dim3(34, 4), 256, 0, stream>>>(
        xnb, 1024, w_inT, 1024, proj, PROJP, 1024, nullptr);
    k_dt<<<64, 256, 0, stream>>>(proj, A_log, dt_bias, dtw, abw);
    k_conv<<<4096, 256, 0, stream>>>(proj, conv_w, conv_b, hconv);
    k_scan1<<<dim3(NCH, 32), 256, 0, stream>>>(proj, hconv, dtw, abw, Sloc, Pc);
    k_scan2<<<512, 256, 0, stream>>>(Sloc, Pc, Sinit);
    k_scan3<<<dim3(NCH, 32), 256, 0, stream>>>(proj, hconv, dtw, abw, Sinit, yg);
    k_gemm<64, 128, 1><<<dim3(8, 8), 256, 0, stream>>>(
        yg, 2048, w_outT, 2048, out, 1024, 2048, x);
}

// Round 3
// 167.744 us; speedup vs baseline: 1.5335x; 1.5335x over previous
//
#include <hip/hip_runtime.h>
#include <hip/hip_bf16.h>

typedef unsigned short u16;
typedef float f32x4v __attribute__((ext_vector_type(4)));
typedef short short8 __attribute__((ext_vector_type(8)));

#define TSEQ 512
#define EMB  1024
#define DI   2048
#define NH   32
#define DS   64
#define PROJ 4256
#define PROJP 4352
#define NCH  8    // chunks
#define LCH  64   // chunk length
#define KSPLIT2 4

__device__ __forceinline__ u16 f2bf(float f) {
    union { __hip_bfloat16 h; u16 u; } cv;
    cv.h = __float2bfloat16(f);
    return cv.u;
}
__device__ __forceinline__ unsigned pack2(float a, float b) {
    return (unsigned)f2bf(a) | ((unsigned)f2bf(b) << 16);
}

// ---------------- transpose + cast f32 (K x N) -> bf16 (Npad x K), zero-pad n >= N
__global__ __launch_bounds__(256) void k_transpose_cast(
        const float* __restrict__ src, u16* __restrict__ dst, int K, int N) {
    __shared__ float tile[64][65];
    const int n0 = blockIdx.x * 64;
    const int k0 = blockIdx.y * 64;
    const int tid = threadIdx.x;
    const int c  = tid & 63;   // n-within (load)
    const int r4 = tid >> 6;
    #pragma unroll
    for (int i = 0; i < 16; ++i) {
        int r = r4 + i * 4;    // k-within
        float v = 0.f;
        if (n0 + c < N) v = src[(size_t)(k0 + r) * N + n0 + c];
        tile[r][c] = v;
    }
    __syncthreads();
    const int rk = tid & 63;   // k-within (store)
    const int cn = tid >> 6;
    #pragma unroll
    for (int i = 0; i < 16; ++i) {
        int n = cn + i * 4;    // n-within
        dst[(size_t)(n0 + n) * K + k0 + rk] = f2bf(tile[rk][n]);
    }
}

// ---------------- RMSNorm -> bf16
__global__ __launch_bounds__(256) void k_rmsnorm(
        const float* __restrict__ x, const float* __restrict__ scale,
        u16* __restrict__ xnb) {
    const int t = blockIdx.x, tid = threadIdx.x;
    const float4* xr = (const float4*)(x + (size_t)t * EMB);
    float4 v = xr[tid];
    float ss = v.x * v.x + v.y * v.y + v.z * v.z + v.w * v.w;
    #pragma unroll
    for (int off = 32; off; off >>= 1) ss += __shfl_xor(ss, off);
    __shared__ float ws4[4];
    if ((tid & 63) == 0) ws4[tid >> 6] = ss;
    __syncthreads();
    float tot = ws4[0] + ws4[1] + ws4[2] + ws4[3];
    float inv = rsqrtf(tot * (1.f / EMB) + 1e-6f);
    float4 s = ((const float4*)scale)[tid];
    uint2 o;
    o.x = pack2(v.x * inv * s.x, v.y * inv * s.y);
    o.y = pack2(v.z * inv * s.z, v.w * inv * s.w);
    ((uint2*)xnb)[(size_t)t * 256 + tid] = o;
}

// ---------------- bf16 MFMA GEMM with register prefetch.
// C[M x N] (or split-K partial) = A[M x K] * BT[N x K]^T
// 256 threads = 4 waves in 2x2; BK = 64. blockIdx.z = K-split index.
template<int BM, int BN>
__global__ __launch_bounds__(256) void k_gemm(
        const u16* __restrict__ A, int lda,
        const u16* __restrict__ BT, int ldb,
        float* __restrict__ C, int ldc, int Kper) {
    constexpr int WM = BM / 2, WN = BN / 2, FM = WM / 16, FN = WN / 16;
    constexpr int NA = BM * 8 / 256, NB = BN * 8 / 256;  // 8-elem chunks per thread
    __shared__ __align__(16) u16 Al[BM][72];
    __shared__ __align__(16) u16 Bl[BN][72];
    const int tid = threadIdx.x;
    const int wid = tid >> 6, lane = tid & 63;
    const int wr = wid >> 1, wc = wid & 1;
    const int ar = lane & 15, kg = lane >> 4;
    const int row0 = blockIdx.y * BM, col0 = blockIdx.x * BN;
    const int kbase = blockIdx.z * Kper;
    const int Mtot = gridDim.y * BM;
    float* Cz = C + (size_t)blockIdx.z * Mtot * ldc;

    short8 ra[NA], rb[NB];
    auto load_stage = [&](int k0) {
        #pragma unroll
        for (int j = 0; j < NA; ++j) {
            int idx = tid + j * 256;
            ra[j] = *(const short8*)(A + (size_t)(row0 + (idx >> 3)) * lda + k0 + (idx & 7) * 8);
        }
        #pragma unroll
        for (int j = 0; j < NB; ++j) {
            int idx = tid + j * 256;
            rb[j] = *(const short8*)(BT + (size_t)(col0 + (idx >> 3)) * ldb + k0 + (idx & 7) * 8);
        }
    };
    auto write_stage = [&]() {
        #pragma unroll
        for (int j = 0; j < NA; ++j) {
            int idx = tid + j * 256;
            *(short8*)&Al[idx >> 3][(idx & 7) * 8] = ra[j];
        }
        #pragma unroll
        for (int j = 0; j < NB; ++j) {
            int idx = tid + j * 256;
            *(short8*)&Bl[idx >> 3][(idx & 7) * 8] = rb[j];
        }
    };

    f32x4v acc[FM][FN] = {};
    const int NT = Kper / 64;
    load_stage(kbase);
    for (int kt = 0; kt < NT; ++kt) {
        write_stage();
        __syncthreads();
        if (kt + 1 < NT) load_stage(kbase + (kt + 1) * 64);  // prefetch overlaps MFMA
        #pragma unroll
        for (int kk = 0; kk < 2; ++kk) {
            short8 af[FM], bf[FN];
            #pragma unroll
            for (int m = 0; m < FM; ++m)
                af[m] = *(const short8*)&Al[wr * WM + m * 16 + ar][kk * 32 + kg * 8];
            #pragma unroll
            for (int n = 0; n < FN; ++n)
                bf[n] = *(const short8*)&Bl[wc * WN + n * 16 + ar][kk * 32 + kg * 8];
            #pragma unroll
            for (int m = 0; m < FM; ++m)
                #pragma unroll
                for (int n = 0; n < FN; ++n)
                    acc[m][n] = __builtin_amdgcn_mfma_f32_16x16x32_bf16(
                        af[m], bf[n], acc[m][n], 0, 0, 0);
        }
        __syncthreads();
    }
    #pragma unroll
    for (int m = 0; m < FM; ++m)
        #pragma unroll
        for (int n = 0; n < FN; ++n)
            #pragma unroll
            for (int j = 0; j < 4; ++j) {
                int row = row0 + wr * WM + m * 16 + kg * 4 + j;
                int col = col0 + wc * WN + n * 16 + ar;
                Cz[(size_t)row * ldc + col] = acc[m][n][j];
            }
}

// ---------------- split-K reduce + residual: out = x + sum_z part[z]
__global__ __launch_bounds__(256) void k_reduce_out(
        const float* __restrict__ part, const float* __restrict__ x,
        float* __restrict__ out) {
    int i = blockIdx.x * 256 + threadIdx.x;   // over 512*1024/4 float4s
    float4 v = ((const float4*)x)[i];
    #pragma unroll
    for (int z = 0; z < KSPLIT2; ++z) {
        float4 p = ((const float4*)part)[(size_t)z * (TSEQ * EMB / 4) + i];
        v.x += p.x; v.y += p.y; v.z += p.z; v.w += p.w;
    }
    ((float4*)out)[i] = v;
}

// ---------------- dt / A_bar
__global__ __launch_bounds__(256) void k_dt(
        const float* __restrict__ proj, const float* __restrict__ A_log,
        const float* __restrict__ dt_bias, float* __restrict__ dtw,
        float* __restrict__ abw) {
    int idx = blockIdx.x * 256 + threadIdx.x;   // < 512*32
    int t = idx >> 5, hh = idx & 31;
    float z = proj[(size_t)t * PROJP + 2 * DI + hh] + dt_bias[hh];
    float dt = (z > 20.f) ? z : log1pf(expf(z));
    float ab = expf(-expf(A_log[hh]) * dt);
    dtw[idx] = dt;
    abw[idx] = ab;
}

// ---------------- causal conv(4) + SiLU
__global__ __launch_bounds__(256) void k_conv(
        const float* __restrict__ proj, const float* __restrict__ cw,
        const float* __restrict__ cb, float* __restrict__ hout) {
    int idx = blockIdx.x * 256 + threadIdx.x;   // < 512*2048
    int t = idx >> 11, c = idx & 2047;
    float acc = cb[c];
    #pragma unroll
    for (int k = 0; k < 4; ++k) {
        int tt = t + k - 3;
        if (tt >= 0) acc += cw[k * DI + c] * proj[(size_t)tt * PROJP + DI + c];
    }
    hout[idx] = acc / (1.f + expf(-acc));
}

// ---------------- scan phase 1: per-(chunk,head) local end-state + decay product
__global__ __launch_bounds__(256) void k_scan1(
        const float* __restrict__ proj, const float* __restrict__ hconv,
        const float* __restrict__ dtw, const float* __restrict__ abw,
        float* __restrict__ Sloc, float* __restrict__ Pc) {
    const int c = blockIdx.x, h = blockIdx.y;
    const int tid = threadIdx.x;
    const int q = tid & 3, p = tid >> 2, n0 = q * 16;
    __shared__ __align__(16) float Blds[64][64];
    __shared__ __align__(16) float xl[64][64];
    __shared__ float al[64], dl[64];
    for (int i = tid; i < 4096; i += 256) {
        int t = i >> 6, n = i & 63;
        Blds[t][n] = proj[(size_t)(c * 64 + t) * PROJP + 2 * DI + NH + n];
        xl[t][n]   = hconv[(size_t)(c * 64 + t) * DI + h * 64 + n];
    }
    if (tid < 64) {
        al[tid] = abw[(c * 64 + tid) * NH + h];
        dl[tid] = dtw[(c * 64 + tid) * NH + h];
    }
    __syncthreads();
    float s[16] = {0.f,0.f,0.f,0.f,0.f,0.f,0.f,0.f,0.f,0.f,0.f,0.f,0.f,0.f,0.f,0.f};
    for (int t = 0; t < 64; ++t) {
        float a = al[t];
        float dtx = dl[t] * xl[t][p];
        const float4* brow = (const float4*)&Blds[t][n0];
        #pragma unroll
        for (int i4 = 0; i4 < 4; ++i4) {
            float4 b = brow[i4];
            s[i4*4+0] = a * s[i4*4+0] + dtx * b.x;
            s[i4*4+1] = a * s[i4*4+1] + dtx * b.y;
            s[i4*4+2] = a * s[i4*4+2] + dtx * b.z;
            s[i4*4+3] = a * s[i4*4+3] + dtx * b.w;
        }
    }
    float* dst = Sloc + ((size_t)(c * 32 + h) * 64 + p) * 64 + n0;
    #pragma unroll
    for (int i4 = 0; i4 < 4; ++i4)
        ((float4*)dst)[i4] = make_float4(s[i4*4], s[i4*4+1], s[i4*4+2], s[i4*4+3]);
    if (tid == 0) {
        float pr = 1.f;
        for (int t = 0; t < 64; ++t) pr *= al[t];
        Pc[c * 32 + h] = pr;
    }
}

// ---------------- scan phase 2: inter-chunk scan (tiny)
__global__ __launch_bounds__(256) void k_scan2(
        const float* __restrict__ Sloc, const float* __restrict__ Pc,
        float* __restrict__ Sinit) {
    int gid = blockIdx.x * 256 + threadIdx.x;   // < 32*4096
    int h = gid >> 12, rem = gid & 4095;
    float s = 0.f;
    #pragma unroll
    for (int c = 0; c < NCH; ++c) {
        size_t o = (size_t)(c * 32 + h) * 4096 + rem;
        Sinit[o] = s;
        s = Pc[c * 32 + h] * s + Sloc[o];
    }
}

// ---------------- scan phase 3: replay with outputs, fused gate*silu -> bf16
__global__ __launch_bounds__(256) void k_scan3(
        const float* __restrict__ proj, const float* __restrict__ hconv,
        const float* __restrict__ dtw, const float* __restrict__ abw,
        const float* __restrict__ Sinit, u16* __restrict__ yg) {
    const int c = blockIdx.x, h = blockIdx.y;
    const int tid = threadIdx.x;
    const int q = tid & 3, p = tid >> 2, n0 = q * 16;
    __shared__ __align__(16) float Blds[64][64];
    __shared__ __align__(16) float Clds[64][64];
    __shared__ __align__(16) float xl[64][64];
    __shared__ float al[64], dl[64];
    for (int i = tid; i < 4096; i += 256) {
        int t = i >> 6, n = i & 63;
        Blds[t][n] = proj[(size_t)(c * 64 + t) * PROJP + 2 * DI + NH + n];
        Clds[t][n] = proj[(size_t)(c * 64 + t) * PROJP + 2 * DI + NH + DS + n];
        xl[t][n]   = hconv[(size_t)(c * 64 + t) * DI + h * 64 + n];
    }
    if (tid < 64) {
        al[tid] = abw[(c * 64 + tid) * NH + h];
        dl[tid] = dtw[(c * 64 + tid) * NH + h];
    }
    __syncthreads();
    float s[16];
    const float* si = Sinit + ((size_t)(c * 32 + h) * 64 + p) * 64 + n0;
    #pragma unroll
    for (int i4 = 0; i4 < 4; ++i4) {
        float4 v = ((const float4*)si)[i4];
        s[i4*4+0] = v.x; s[i4*4+1] = v.y; s[i4*4+2] = v.z; s[i4*4+3] = v.w;
    }
    for (int t = 0; t < 64; ++t) {
        float a = al[t];
        float dtx = dl[t] * xl[t][p];
        const float4* brow = (const float4*)&Blds[t][n0];
        const float4* crow = (const float4*)&Clds[t][n0];
        float yp = 0.f;
        #pragma unroll
        for (int i4 = 0; i4 < 4; ++i4) {
            float4 b = brow[i4], cc = crow[i4];
            s[i4*4+0] = a * s[i4*4+0] + dtx * b.x; yp += s[i4*4+0] * cc.x;
            s[i4*4+1] = a * s[i4*4+1] + dtx * b.y; yp += s[i4*4+1] * cc.y;
            s[i4*4+2] = a * s[i4*4+2] + dtx * b.z; yp += s[i4*4+2] * cc.z;
            s[i4*4+3] = a * s[i4*4+3] + dtx * b.w; yp += s[i4*4+3] * cc.w;
        }
        yp += __shfl_xor(yp, 1);
        yp += __shfl_xor(yp, 2);
        if (q == 0) xl[t][p] = yp;   // reuse xl as y storage (same-wave safe)
    }
    __syncthreads();
    for (int i = tid; i < 4096; i += 256) {
        int t = i >> 6, pp = i & 63;
        float y = xl[t][pp];
        float g = proj[(size_t)(c * 64 + t) * PROJP + h * 64 + pp];
        float gy = y * (g / (1.f + expf(-g)));
        yg[(size_t)(c * 64 + t) * DI + h * 64 + pp] = f2bf(gy);
    }
}

extern "C" void kernel_launch(void* const* d_in, const int* in_sizes, int n_in,
                              void* d_out, int out_size, void* d_ws, size_t ws_size,
                              hipStream_t stream) {
    (void)in_sizes; (void)n_in; (void)out_size; (void)ws_size;
    const float* x       = (const float*)d_in[0];
    const float* nscale  = (const float*)d_in[1];
    const float* w_in    = (const float*)d_in[2];
    const float* conv_w  = (const float*)d_in[3];
    const float* conv_b  = (const float*)d_in[4];
    const float* A_log   = (const float*)d_in[5];
    const float* dt_bias = (const float*)d_in[6];
    const float* w_out   = (const float*)d_in[7];
    float* out = (float*)d_out;

    char* wsp = (char*)d_ws;
    auto alloc = [&](size_t bytes) {
        char* ptr = wsp;
        wsp += (bytes + 255) & ~(size_t)255;
        return ptr;
    };
    u16*   w_inT  = (u16*)  alloc((size_t)PROJP * 1024 * 2);
    u16*   w_outT = (u16*)  alloc((size_t)1024 * 2048 * 2);
    u16*   xnb    = (u16*)  alloc((size_t)512 * 1024 * 2);
    float* proj   = (float*)alloc((size_t)512 * PROJP * 4);
    float* hconv  = (float*)alloc((size_t)512 * 2048 * 4);
    float* dtw    = (float*)alloc((size_t)512 * 32 * 4);
    float* abw    = (float*)alloc((size_t)512 * 32 * 4);
    float* Pc     = (float*)alloc((size_t)256 * 4);
    float* Sloc   = (float*)alloc((size_t)NCH * 32 * 4096 * 4);
    float* Sinit  = (float*)alloc((size_t)NCH * 32 * 4096 * 4);
    u16*   yg     = (u16*)  alloc((size_t)512 * 2048 * 2);
    float* part2  = (float*)alloc((size_t)KSPLIT2 * 512 * 1024 * 4);

    k_transpose_cast<<<dim3(68, 16), 256, 0, stream>>>(w_in, w_inT, 1024, PROJ);
    k_transpose_cast<<<dim3(16, 32), 256, 0, stream>>>(w_out, w_outT, 2048, 1024);
    k_rmsnorm<<<512, 256, 0, stream>>>(x, nscale, xnb);
    k_gemm<64, 128><<<dim3(34, 8, 1), 256, 0, stream>>>(
        xnb, 1024, w_inT, 1024, proj, PROJP, 1024);
    k_dt<<<64, 256, 0, stream>>>(proj, A_log, dt_bias, dtw, abw);
    k_conv<<<4096, 256, 0, stream>>>(proj, conv_w, conv_b, hconv);
    k_scan1<<<dim3(NCH, 32), 256, 0, stream>>>(proj, hconv, dtw, abw, Sloc, Pc);
    k_scan2<<<512, 256, 0, stream>>>(Sloc, Pc, Sinit);
    k_scan3<<<dim3(NCH, 32), 256, 0, stream>>>(proj, hconv, dtw, abw, Sinit, yg);
    k_gemm<64, 128><<<dim3(8, 8, KSPLIT2), 256, 0, stream>>>(
        yg, 2048, w_outT, 2048, part2, 1024, 2048 / KSPLIT2);
    k_reduce_out<<<512, 256, 0, stream>>>(part2, x, out);
}